// Round 11
// baseline (63.187 us; speedup 1.0000x reference)
//
#include <hip/hip_runtime.h>

#define H 128
#define NPOS 10
#define ROWSB 32
#define BLOCK 512

using bf16x8 = __attribute__((ext_vector_type(8))) short;
using f32x4  = __attribute__((ext_vector_type(4))) float;

__device__ __forceinline__ unsigned short f2bf(float f) {
  unsigned u = __float_as_uint(f);
  u += 0x7FFFu + ((u >> 16) & 1u);   // round-to-nearest-even
  return (unsigned short)(u >> 16);
}
__device__ __forceinline__ float bf2f(unsigned short s) {
  return __uint_as_float(((unsigned)s) << 16);
}
__device__ __forceinline__ float sigm(float x) {
  return __builtin_amdgcn_rcpf(1.0f + __builtin_amdgcn_exp2f(-1.44269504f * x));
}
__device__ __forceinline__ float tanh_f(float x) {
  return 2.0f * __builtin_amdgcn_rcpf(1.0f + __builtin_amdgcn_exp2f(-2.88539008f * x)) - 1.0f;
}

// K1: weights prep + per-block pos histogram (no global atomics, no memset).
__global__ void prep_wt(const float* __restrict__ Wf, const float* __restrict__ Wiou,
                        unsigned short* __restrict__ wt,
                        const int* __restrict__ posp, int* __restrict__ hist2,
                        int N, int nhb) {
  int b = blockIdx.x, t = threadIdx.x;
  if (b < NPOS * 16) {
    __shared__ float tile[32][33];
    int p = b >> 4, jt = (b >> 2) & 3, kt = b & 3;
    int tx = t & 31, ty = t >> 5;            // 32 x 8
    #pragma unroll
    for (int it = 0; it < 4; ++it) {
      int krow = kt * 32 + ty + it * 8;
      int j = jt * 32 + tx;
      tile[ty + it * 8][tx] = Wf[(size_t)(p * H + krow) * H + j];
    }
    __syncthreads();
    #pragma unroll
    for (int it = 0; it < 4; ++it) {
      int j2 = jt * 32 + ty + it * 8;
      int k2 = kt * 32 + tx;
      wt[(size_t)p * 512 * H + (size_t)j2 * H + k2] = f2bf(tile[tx][ty + it * 8]);
    }
  } else if (b < NPOS * 16 + (NPOS * 384 * H) / 256) {
    int id = (b - NPOS * 16) * 256 + t;
    int p = id / 49152;
    int r = id - p * 49152;
    int k = r & 127;
    float v = Wiou[(size_t)(r >> 7) * (NPOS * H) + p * H + k];
    wt[(size_t)p * 65536 + 16384 + r] = f2bf(v);
  } else {
    int hb = b - (NPOS * 16 + (NPOS * 384 * H) / 256);
    __shared__ int c[NPOS];
    if (t < NPOS) c[t] = 0;
    __syncthreads();
    int i = hb * 256 + t;
    if (i < N) atomicAdd(&c[posp[i]], 1);    // LDS atomic only
    __syncthreads();
    if (t < NPOS) hist2[hb * 16 + t] = c[t];
  }
}

// K2: wave-parallel scans (10 waves, wave w owns pos w).
__global__ void scan_build(const int* __restrict__ hist2, int nhb,
                           int* __restrict__ off2,
                           int* __restrict__ blkpos, int* __restrict__ blkgs,
                           int* __restrict__ blkcnt, int maxb) {
  __shared__ int tot[NPOS], base[NPOS + 1], bb[NPOS + 1];
  int t = threadIdx.x;
  int w = t >> 6, l = t & 63;
  if (w < NPOS) {
    int b0 = 2 * l, b1 = 2 * l + 1;
    int a  = (b0 < nhb) ? hist2[b0 * 16 + w] : 0;
    int bv = (b1 < nhb) ? hist2[b1 * 16 + w] : 0;
    int s = a + bv, sc = s;
    #pragma unroll
    for (int off = 1; off < 64; off <<= 1) {
      int u = __shfl_up(sc, off);
      if (l >= off) sc += u;
    }
    int excl = sc - s;
    if (b0 < nhb) off2[b0 * 16 + w] = excl;
    if (b1 < nhb) off2[b1 * 16 + w] = excl + a;
    if (l == 63) tot[w] = sc;
  }
  __syncthreads();
  if (t == 0) {
    int run = 0, rb = 0;
    for (int p = 0; p < NPOS; ++p) {
      base[p] = run; bb[p] = rb;
      run += tot[p];
      rb += (tot[p] + ROWSB - 1) / ROWSB;
    }
    base[NPOS] = run; bb[NPOS] = rb;
  }
  __syncthreads();
  for (int i = t; i < nhb * NPOS; i += 640) {
    int b = i / NPOS, p = i - b * NPOS;
    off2[b * 16 + p] += base[p];
  }
  int nb = bb[NPOS];
  for (int b = t; b < maxb; b += 640) {
    if (b < nb) {
      int p = 0;
      while (bb[p + 1] <= b) ++p;
      int s = (b - bb[p]) * ROWSB;
      blkpos[b] = p;
      blkgs[b] = base[p] + s;
      blkcnt[b] = min(ROWSB, tot[p] - s);
    } else {
      blkpos[b] = -1;
    }
  }
}

// K3: scatter + natural->sorted rank map (all coalesced / LDS atomics only).
__global__ void scatter_idx(const int* __restrict__ posp, const int* __restrict__ depthp,
                            const int* __restrict__ maskp, const int* __restrict__ off2,
                            unsigned* __restrict__ order, int* __restrict__ rank, int N) {
  __shared__ int c[NPOS], basearr[NPOS];
  int hb = blockIdx.x, t = threadIdx.x;
  if (t < NPOS) { c[t] = 0; basearr[t] = off2[hb * 16 + t]; }
  __syncthreads();
  int i = hb * 256 + t;
  int p = -1, r = 0;
  unsigned e = 0;
  if (i < N) {
    p = posp[i];
    r = atomicAdd(&c[p], 1);                 // LDS atomic only
    int d = depthp[i];
    int mk = maskp[i];
    e = (unsigned)i | ((unsigned)mk << 16) |
        ((unsigned)(d == 1) << 17) | ((unsigned)(d == 2) << 18);
  }
  __syncthreads();
  if (p >= 0) {
    int s = basearr[p] + r;
    order[s] = e;
    rank[i] = s;                             // coalesced in i
  }
}

// MODE 0: inline epilogue (fallback, R10 behavior).
// MODE 1: write packed bf16 gates {u,i,o,g} per (sorted row, col) -> streaming.
template <int MODE>
__global__ __launch_bounds__(BLOCK, 3) void tree_lstm_main(
    const float* __restrict__ child_h, const float* __restrict__ child_c,
    const float* __restrict__ e1, const float* __restrict__ e2,
    const float* __restrict__ h_prev,
    const float* __restrict__ b_f, const float* __restrict__ b_iou,
    const unsigned short* __restrict__ wt,
    const unsigned* __restrict__ order, const int* __restrict__ blkpos,
    const int* __restrict__ blkgs, const int* __restrict__ blkcnt,
    unsigned short* __restrict__ gates, float* __restrict__ out, int N) {

  const int b = blockIdx.x;
  const int p = blkpos[b];
  if (p < 0) return;
  const int gs = blkgs[b], cnth = blkcnt[b];

  __shared__ unsigned short hs[ROWSB * H];   // 8 KB, XOR-swizzled bf16 h_cat
  __shared__ unsigned rowg[ROWSB];

  const int t = threadIdx.x;
  const int wv = t >> 6, l = t & 63;
  const int l15 = l & 15, lhi = l >> 4;
  const int colr = wv * 16 + l15;
  const int kof = lhi * 8;

  const unsigned short* wb0 = wt + (size_t)p * 512 * H + (size_t)colr * H + kof;

  if (t < ROWSB) rowg[t] = (t < cnth) ? order[gs + t] : 0xFFFFFFFFu;
  __syncthreads();

  // ---- stage A: 32 rows x 128 bf16 (child_h + depth-class extras) ----
  {
    int row = t >> 4, c8 = t & 15;
    unsigned e = rowg[row];
    float4 a0 = {0.f, 0.f, 0.f, 0.f}, a1 = {0.f, 0.f, 0.f, 0.f};
    if ((int)e >= 0) {
      int g = e & 0xFFFF;
      const float4* ph = (const float4*)(child_h + (size_t)g * H + c8 * 8);
      a0 = ph[0]; a1 = ph[1];
      if (e & (3u << 17)) {
        const float* ep = (e & (1u << 17)) ? e1 : e2;
        const float4* pe = (const float4*)(ep + (size_t)g * H + c8 * 8);
        float4 b0 = pe[0], b1 = pe[1];
        a0.x += b0.x; a0.y += b0.y; a0.z += b0.z; a0.w += b0.w;
        a1.x += b1.x; a1.y += b1.y; a1.z += b1.z; a1.w += b1.w;
      }
    }
    bf16x8 v;
    v[0] = (short)f2bf(a0.x); v[1] = (short)f2bf(a0.y);
    v[2] = (short)f2bf(a0.z); v[3] = (short)f2bf(a0.w);
    v[4] = (short)f2bf(a1.x); v[5] = (short)f2bf(a1.y);
    v[6] = (short)f2bf(a1.z); v[7] = (short)f2bf(a1.w);
    int wb = (row * 256 + c8 * 16) ^ ((row & 7) << 4);
    *(bf16x8*)((char*)hs + wb) = v;
  }
  __syncthreads();

  const size_t NH = (size_t)N * H;
  const float bfv = b_f[p * H + colr];
  const float b_i = b_iou[colr], b_o = b_iou[H + colr], b_g = b_iou[2 * H + colr];

  const int nchunk = (cnth + 15) >> 4;
  for (int c = 0; c < nchunk; ++c) {
    const int r0 = c * 16;

    bf16x8 Bu[4], Biq[4], Boq[4], Bgq[4];
    #pragma unroll
    for (int kk = 0; kk < 4; ++kk) {
      Bu[kk]  = *(const bf16x8*)(wb0 + kk * 32);
      Biq[kk] = *(const bf16x8*)(wb0 + 128 * H + kk * 32);
      Boq[kk] = *(const bf16x8*)(wb0 + 256 * H + kk * 32);
      Bgq[kk] = *(const bf16x8*)(wb0 + 384 * H + kk * 32);
    }

    unsigned gg[4]; float cc[4], hpv[4];
    if (MODE == 0) {
      #pragma unroll
      for (int q = 0; q < 4; ++q) {
        int rr = r0 + lhi * 4 + q;
        gg[q] = (rr < cnth) ? rowg[rr] : 0xFFFFFFFFu;
      }
      #pragma unroll
      for (int q = 0; q < 4; ++q) {
        if ((int)gg[q] >= 0) {
          size_t gi = (size_t)(gg[q] & 0xFFFF) * H + colr;
          cc[q] = child_c[gi];
          hpv[q] = h_prev[gi];
        } else { cc[q] = 0.f; hpv[q] = 0.f; }
      }
    }

    const int arow = r0 + l15;
    bf16x8 afr[4];
    #pragma unroll
    for (int kk = 0; kk < 4; ++kk) {
      int rb = (arow * 256 + kk * 64 + lhi * 16) ^ ((arow & 7) << 4);
      afr[kk] = *(const bf16x8*)((const char*)hs + rb);
    }

    f32x4 au = {0.f, 0.f, 0.f, 0.f};
    f32x4 ai = {0.f, 0.f, 0.f, 0.f};
    f32x4 ao = {0.f, 0.f, 0.f, 0.f};
    f32x4 ag = {0.f, 0.f, 0.f, 0.f};
    #pragma unroll
    for (int kk = 0; kk < 4; ++kk) {
      au = __builtin_amdgcn_mfma_f32_16x16x32_bf16(afr[kk], Bu[kk],  au, 0, 0, 0);
      ai = __builtin_amdgcn_mfma_f32_16x16x32_bf16(afr[kk], Biq[kk], ai, 0, 0, 0);
      ao = __builtin_amdgcn_mfma_f32_16x16x32_bf16(afr[kk], Boq[kk], ao, 0, 0, 0);
      ag = __builtin_amdgcn_mfma_f32_16x16x32_bf16(afr[kk], Bgq[kk], ag, 0, 0, 0);
    }

    #pragma unroll
    for (int q = 0; q < 4; ++q) {
      int rr = r0 + lhi * 4 + q;
      if (MODE == 1) {
        // streaming gate write at SORTED row gs+rr (1 KB/row, full lines)
        if (rr < cnth) {
          ushort4 gvv;
          gvv.x = f2bf(au[q] + bfv);
          gvv.y = f2bf(ai[q] + b_i);
          gvv.z = f2bf(ao[q] + b_o);
          gvv.w = f2bf(ag[q] + b_g);
          *(ushort4*)(gates + (size_t)(gs + rr) * 512 + colr * 4) = gvv;
        }
      } else {
        if ((int)gg[q] >= 0) {
          size_t gi = (size_t)(gg[q] & 0xFFFF) * H + colr;
          float u = au[q] + bfv;
          float iv = ai[q] + b_i;
          float ov = ao[q] + b_o;
          float gv = ag[q] + b_g;
          float f = sigm(u);
          float credv = f * cc[q];
          float cnew = sigm(iv) * tanh_f(gv) + credv;
          float hnew = sigm(ov) * tanh_f(cnew);
          float m = (float)((gg[q] >> 16) & 1u);
          float hv = hpv[q] * m + (1.0f - m) * hnew;
          float cv = credv * m + (1.0f - m) * cnew;
          out[gi] = hv;
          out[NH + gi] = cv;
        }
      }
    }
  }
}

// K5: streaming epilogue in NATURAL row order. All reads/writes coalesced.
__global__ __launch_bounds__(512) void epilogue_k(
    const unsigned short* __restrict__ gates, const int* __restrict__ rank,
    const float* __restrict__ child_c, const float* __restrict__ h_prev,
    const int* __restrict__ maskp, float* __restrict__ out, int N) {
  const int t = threadIdx.x;
  const int col = t & 127;
  const size_t NH = (size_t)N * H;
  #pragma unroll
  for (int it = 0; it < 4; ++it) {
    int i = blockIdx.x * 16 + it * 4 + (t >> 7);
    int r = rank[i];                          // broadcast within 128-group
    float m = (float)maskp[i];
    ushort4 gvv = *(const ushort4*)(gates + (size_t)r * 512 + col * 4);
    size_t gi = (size_t)i * H + col;
    float cc = child_c[gi];
    float hp = h_prev[gi];
    float u = bf2f(gvv.x), iv = bf2f(gvv.y), ov = bf2f(gvv.z), gv = bf2f(gvv.w);
    float f = sigm(u);
    float credv = f * cc;
    float cnew = sigm(iv) * tanh_f(gv) + credv;
    float hnew = sigm(ov) * tanh_f(cnew);
    float hv = hp * m + (1.0f - m) * hnew;
    float cv = credv * m + (1.0f - m) * cnew;
    __builtin_nontemporal_store(hv, &out[gi]);        // full-line streaming
    __builtin_nontemporal_store(cv, &out[NH + gi]);
  }
}

extern "C" void kernel_launch(void* const* d_in, const int* in_sizes, int n_in,
                              void* d_out, int out_size, void* d_ws, size_t ws_size,
                              hipStream_t stream) {
  const float* child_h = (const float*)d_in[0];
  const float* child_c = (const float*)d_in[1];
  const float* e1      = (const float*)d_in[2];
  const float* e2      = (const float*)d_in[3];
  const float* h_prev  = (const float*)d_in[4];
  const int*   posp    = (const int*)d_in[5];
  const int*   depthp  = (const int*)d_in[6];
  const int*   maskp   = (const int*)d_in[7];
  const float* W_f     = (const float*)d_in[8];
  const float* b_f     = (const float*)d_in[9];
  const float* W_iou   = (const float*)d_in[10];
  const float* b_iou   = (const float*)d_in[11];
  float* out = (float*)d_out;
  int N = in_sizes[0] / H;
  int nhb = (N + 255) / 256;
  int maxb = NPOS + N / ROWSB;

  const size_t wt_bytes    = (size_t)NPOS * 512 * H * 2;        // 1.31 MB
  const size_t gates_bytes = (size_t)N * 512;                    // 16.7 MB... (N*512 ushorts? no: bytes)
  // gates: N rows * 512 ushorts * 2B = N*1024 bytes
  const size_t gates_b     = (size_t)N * 1024;
  const size_t table_b     = (size_t)(nhb * 32 + maxb * 3 + 16) * 4 + (size_t)N * 8;

  bool split = ws_size >= wt_bytes + gates_b + table_b + 1024;

  unsigned short* wt = (unsigned short*)d_ws;
  char* cur = (char*)d_ws + wt_bytes;
  unsigned short* gates = nullptr;
  if (split) { gates = (unsigned short*)cur; cur += gates_b; }
  int* hist2  = (int*)cur;
  int* off2   = hist2 + nhb * 16;
  int* blkpos = off2 + nhb * 16;
  int* blkgs  = blkpos + maxb;
  int* blkcnt = blkgs + maxb;
  unsigned* order = (unsigned*)(blkcnt + maxb);
  int* rank = (int*)(order + N);

  int prep_blocks = NPOS * 16 + (NPOS * 384 * H) / 256 + nhb;
  hipLaunchKernelGGL(prep_wt, dim3(prep_blocks), dim3(256), 0, stream,
                     W_f, W_iou, wt, posp, hist2, N, nhb);
  hipLaunchKernelGGL(scan_build, dim3(1), dim3(640), 0, stream,
                     hist2, nhb, off2, blkpos, blkgs, blkcnt, maxb);
  hipLaunchKernelGGL(scatter_idx, dim3(nhb), dim3(256), 0, stream,
                     posp, depthp, maskp, off2, order, rank, N);
  if (split) {
    hipLaunchKernelGGL((tree_lstm_main<1>), dim3(maxb), dim3(BLOCK), 0, stream,
                       child_h, child_c, e1, e2, h_prev,
                       b_f, b_iou, wt, order, blkpos, blkgs, blkcnt, gates, out, N);
    hipLaunchKernelGGL(epilogue_k, dim3(N / 16), dim3(512), 0, stream,
                       gates, rank, child_c, h_prev, maskp, out, N);
  } else {
    hipLaunchKernelGGL((tree_lstm_main<0>), dim3(maxb), dim3(BLOCK), 0, stream,
                       child_h, child_c, e1, e2, h_prev,
                       b_f, b_iou, wt, order, blkpos, blkgs, blkcnt, gates, out, N);
  }
}

// Round 12
// 47.242 us; speedup vs baseline: 1.3375x; 1.3375x over previous
//
#include <hip/hip_runtime.h>

#define H 128
#define NPOS 10
#define ROWSB 32
#define BLOCK 512

using bf16x8 = __attribute__((ext_vector_type(8))) short;
using f32x4  = __attribute__((ext_vector_type(4))) float;

__device__ __forceinline__ unsigned short f2bf(float f) {
  unsigned u = __float_as_uint(f);
  u += 0x7FFFu + ((u >> 16) & 1u);   // round-to-nearest-even
  return (unsigned short)(u >> 16);
}
__device__ __forceinline__ float sigm(float x) {
  return __builtin_amdgcn_rcpf(1.0f + __builtin_amdgcn_exp2f(-1.44269504f * x));
}
__device__ __forceinline__ float tanh_f(float x) {
  return 2.0f * __builtin_amdgcn_rcpf(1.0f + __builtin_amdgcn_exp2f(-2.88539008f * x)) - 1.0f;
}

// K1: weights prep (k-major fragment layout) + per-block pos histogram.
// wt elem offset = (((p*4+kk)*4 + lhi)*512 + j)*8 + e   where k = kk*32+lhi*8+e,
// j in [0,512): j<128 -> u-gate col j (from W_f), j>=128 -> iou row j-128 (from W_iou).
// Per (p,kk): contiguous 16384 elems = 32 KB slab (staged to LDS by main kernel).
__global__ void prep_wt(const float* __restrict__ Wf, const float* __restrict__ Wiou,
                        unsigned short* __restrict__ wt,
                        const int* __restrict__ posp, int* __restrict__ hist2,
                        int N, int nhb) {
  int b = blockIdx.x, t = threadIdx.x;
  if (b < NPOS * 16) {
    __shared__ float tile[32][33];
    int p = b >> 4, jt = (b >> 2) & 3, kt = b & 3;
    int tx = t & 31, ty = t >> 5;            // 32 x 8
    #pragma unroll
    for (int it = 0; it < 4; ++it) {
      int krow = kt * 32 + ty + it * 8;
      int j = jt * 32 + tx;
      tile[ty + it * 8][tx] = Wf[(size_t)(p * H + krow) * H + j];
    }
    __syncthreads();
    #pragma unroll
    for (int it = 0; it < 4; ++it) {
      int j2 = jt * 32 + ty + it * 8;        // u-gate col
      int k2 = kt * 32 + tx;                 // k index; kk = kt, lhi = tx>>3, e = tx&7
      size_t dst = (((size_t)(p * 4 + kt) * 4 + (tx >> 3)) * 512 + j2) * 8 + (tx & 7);
      wt[dst] = f2bf(tile[tx][ty + it * 8]);
    }
  } else if (b < NPOS * 16 + (NPOS * 384 * H) / 256) {
    int id = (b - NPOS * 16) * 256 + t;      // < 10*384*128
    int p = id / 49152;
    int r = id - p * 49152;                  // (j-128)*128 + k
    int j = 128 + (r >> 7);
    int k = r & 127;
    float v = Wiou[(size_t)(r >> 7) * (NPOS * H) + p * H + k];
    size_t dst = (((size_t)(p * 4 + (k >> 5)) * 4 + ((k >> 3) & 3)) * 512 + j) * 8 + (k & 7);
    wt[dst] = f2bf(v);
  } else {
    int hb = b - (NPOS * 16 + (NPOS * 384 * H) / 256);
    __shared__ int c[NPOS];
    if (t < NPOS) c[t] = 0;
    __syncthreads();
    int i = hb * 256 + t;
    if (i < N) atomicAdd(&c[posp[i]], 1);    // LDS atomic only
    __syncthreads();
    if (t < NPOS) hist2[hb * 16 + t] = c[t];
  }
}

// K2: wave-parallel scans (10 waves, wave w owns pos w).
__global__ void scan_build(const int* __restrict__ hist2, int nhb,
                           int* __restrict__ off2,
                           int* __restrict__ blkpos, int* __restrict__ blkgs,
                           int* __restrict__ blkcnt, int maxb) {
  __shared__ int tot[NPOS], base[NPOS + 1], bb[NPOS + 1];
  int t = threadIdx.x;
  int w = t >> 6, l = t & 63;
  if (w < NPOS) {
    int b0 = 2 * l, b1 = 2 * l + 1;
    int a  = (b0 < nhb) ? hist2[b0 * 16 + w] : 0;
    int bv = (b1 < nhb) ? hist2[b1 * 16 + w] : 0;
    int s = a + bv, sc = s;
    #pragma unroll
    for (int off = 1; off < 64; off <<= 1) {
      int u = __shfl_up(sc, off);
      if (l >= off) sc += u;
    }
    int excl = sc - s;
    if (b0 < nhb) off2[b0 * 16 + w] = excl;
    if (b1 < nhb) off2[b1 * 16 + w] = excl + a;
    if (l == 63) tot[w] = sc;
  }
  __syncthreads();
  if (t == 0) {
    int run = 0, rb = 0;
    for (int p = 0; p < NPOS; ++p) {
      base[p] = run; bb[p] = rb;
      run += tot[p];
      rb += (tot[p] + ROWSB - 1) / ROWSB;
    }
    base[NPOS] = run; bb[NPOS] = rb;
  }
  __syncthreads();
  for (int i = t; i < nhb * NPOS; i += 640) {
    int b = i / NPOS, p = i - b * NPOS;
    off2[b * 16 + p] += base[p];
  }
  int nb = bb[NPOS];
  for (int b = t; b < maxb; b += 640) {
    if (b < nb) {
      int p = 0;
      while (bb[p + 1] <= b) ++p;
      int s = (b - bb[p]) * ROWSB;
      blkpos[b] = p;
      blkgs[b] = base[p] + s;
      blkcnt[b] = min(ROWSB, tot[p] - s);
    } else {
      blkpos[b] = -1;
    }
  }
}

// K3: scatter (LDS atomics + precomputed per-(block,pos) bases).
// order entry packs: g (bits 0..15) | mask<<16 | (depth==1)<<17 | (depth==2)<<18
__global__ void scatter_idx(const int* __restrict__ posp, const int* __restrict__ depthp,
                            const int* __restrict__ maskp, const int* __restrict__ off2,
                            unsigned* __restrict__ order, int N) {
  __shared__ int c[NPOS], basearr[NPOS];
  int hb = blockIdx.x, t = threadIdx.x;
  if (t < NPOS) { c[t] = 0; basearr[t] = off2[hb * 16 + t]; }
  __syncthreads();
  int i = hb * 256 + t;
  int p = -1, r = 0;
  unsigned e = 0;
  if (i < N) {
    p = posp[i];
    r = atomicAdd(&c[p], 1);                 // LDS atomic only
    int d = depthp[i];
    int mk = maskp[i];
    e = (unsigned)i | ((unsigned)mk << 16) |
        ((unsigned)(d == 1) << 17) | ((unsigned)(d == 2) << 18);
  }
  __syncthreads();
  if (p >= 0) order[basearr[p] + r] = e;
}

// K4: main. B panel staged kk-slab-wise into LDS (coalesced, shared by 8 waves,
// reused by both chunks) -> MFMA depends only on lgkm; epilogue gathers hoisted
// above the whole kk loop so HBM/L3 latency hides under matrix work.
__global__ __launch_bounds__(BLOCK, 3) void tree_lstm_main(
    const float* __restrict__ child_h, const float* __restrict__ child_c,
    const float* __restrict__ e1, const float* __restrict__ e2,
    const float* __restrict__ h_prev,
    const float* __restrict__ b_f, const float* __restrict__ b_iou,
    const unsigned short* __restrict__ wt,
    const unsigned* __restrict__ order, const int* __restrict__ blkpos,
    const int* __restrict__ blkgs, const int* __restrict__ blkcnt,
    float* __restrict__ out, int N) {

  const int b = blockIdx.x;
  const int p = blkpos[b];
  if (p < 0) return;
  const int gs = blkgs[b], cnth = blkcnt[b];

  __shared__ unsigned short hs[ROWSB * H];   // 8 KB, XOR-swizzled bf16 h_cat
  __shared__ unsigned short Bs[4 * 512 * 8]; // 32 KB, one kk-slab of B panel
  __shared__ unsigned rowg[ROWSB];

  const int t = threadIdx.x;
  const int wv = t >> 6, l = t & 63;
  const int l15 = l & 15, lhi = l >> 4;
  const int colr = wv * 16 + l15;            // wave's output column 0..127

  if (t < ROWSB) rowg[t] = (t < cnth) ? order[gs + t] : 0xFFFFFFFFu;
  __syncthreads();

  // ---- stage A: 32 rows x 128 bf16 (child_h + depth-class extras) ----
  {
    int row = t >> 4, c8 = t & 15;
    unsigned e = rowg[row];
    float4 a0 = {0.f, 0.f, 0.f, 0.f}, a1 = {0.f, 0.f, 0.f, 0.f};
    if ((int)e >= 0) {
      int g = e & 0xFFFF;
      const float4* ph = (const float4*)(child_h + (size_t)g * H + c8 * 8);
      a0 = ph[0]; a1 = ph[1];
      if (e & (3u << 17)) {
        const float* ep = (e & (1u << 17)) ? e1 : e2;
        const float4* pe = (const float4*)(ep + (size_t)g * H + c8 * 8);
        float4 b0 = pe[0], b1 = pe[1];
        a0.x += b0.x; a0.y += b0.y; a0.z += b0.z; a0.w += b0.w;
        a1.x += b1.x; a1.y += b1.y; a1.z += b1.z; a1.w += b1.w;
      }
    }
    bf16x8 v;
    v[0] = (short)f2bf(a0.x); v[1] = (short)f2bf(a0.y);
    v[2] = (short)f2bf(a0.z); v[3] = (short)f2bf(a0.w);
    v[4] = (short)f2bf(a1.x); v[5] = (short)f2bf(a1.y);
    v[6] = (short)f2bf(a1.z); v[7] = (short)f2bf(a1.w);
    int wb = (row * 256 + c8 * 16) ^ ((row & 7) << 4);
    *(bf16x8*)((char*)hs + wb) = v;
  }

  // ---- hoisted epilogue gathers for BOTH chunks (latency hides under MFMAs) ----
  unsigned gg[2][4]; float cc[2][4], hpv[2][4];
  #pragma unroll
  for (int c = 0; c < 2; ++c)
    #pragma unroll
    for (int q = 0; q < 4; ++q) {
      int rr = c * 16 + lhi * 4 + q;
      unsigned e = (rr < cnth) ? rowg[rr] : 0xFFFFFFFFu;
      gg[c][q] = e;
      if ((int)e >= 0) {
        size_t gi = (size_t)(e & 0xFFFF) * H + colr;
        cc[c][q] = child_c[gi];
        hpv[c][q] = h_prev[gi];
      } else { cc[c][q] = 0.f; hpv[c][q] = 0.f; }
    }

  __syncthreads();                            // hs ready

  f32x4 acc[2][4] = {};
  const unsigned short* wtp = wt + (size_t)p * 65536;

  #pragma unroll
  for (int kk = 0; kk < 4; ++kk) {
    if (kk) __syncthreads();                  // all waves done reading prev Bs
    // stage kk-slab: 32 KB, coalesced global, 16B-interleaved LDS (bank-friendly)
    #pragma unroll
    for (int i = 0; i < 4; ++i) {
      int eo = (i * BLOCK + t) * 8;
      *(bf16x8*)(Bs + eo) = *(const bf16x8*)(wtp + kk * 16384 + eo);
    }
    __syncthreads();

    bf16x8 bfr[4];
    #pragma unroll
    for (int g4 = 0; g4 < 4; ++g4)
      bfr[g4] = *(const bf16x8*)(Bs + ((lhi * 512) + (g4 * 128 + colr)) * 8);

    #pragma unroll
    for (int c = 0; c < 2; ++c) {
      const int arow = c * 16 + l15;
      int rb = (arow * 256 + kk * 64 + lhi * 16) ^ ((arow & 7) << 4);
      bf16x8 afr = *(const bf16x8*)((const char*)hs + rb);
      #pragma unroll
      for (int g4 = 0; g4 < 4; ++g4)
        acc[c][g4] = __builtin_amdgcn_mfma_f32_16x16x32_bf16(afr, bfr[g4], acc[c][g4], 0, 0, 0);
    }
  }

  // ---- epilogue: D row = (l>>4)*4 + q, col = l&15 (verified mapping) ----
  const size_t NH = (size_t)N * H;
  const float bfv = b_f[p * H + colr];
  const float b_i = b_iou[colr], b_o = b_iou[H + colr], b_g = b_iou[2 * H + colr];

  #pragma unroll
  for (int c = 0; c < 2; ++c)
    #pragma unroll
    for (int q = 0; q < 4; ++q) {
      if ((int)gg[c][q] >= 0) {
        size_t gi = (size_t)(gg[c][q] & 0xFFFF) * H + colr;
        float u  = acc[c][0][q] + bfv;
        float iv = acc[c][1][q] + b_i;
        float ov = acc[c][2][q] + b_o;
        float gv = acc[c][3][q] + b_g;
        float f = sigm(u);
        float credv = f * cc[c][q];
        float cnew = sigm(iv) * tanh_f(gv) + credv;
        float hnew = sigm(ov) * tanh_f(cnew);
        float m = (float)((gg[c][q] >> 16) & 1u);
        float hv = hpv[c][q] * m + (1.0f - m) * hnew;
        float cv = credv * m + (1.0f - m) * cnew;
        out[gi] = hv;
        out[NH + gi] = cv;
      }
    }
}

extern "C" void kernel_launch(void* const* d_in, const int* in_sizes, int n_in,
                              void* d_out, int out_size, void* d_ws, size_t ws_size,
                              hipStream_t stream) {
  const float* child_h = (const float*)d_in[0];
  const float* child_c = (const float*)d_in[1];
  const float* e1      = (const float*)d_in[2];
  const float* e2      = (const float*)d_in[3];
  const float* h_prev  = (const float*)d_in[4];
  const int*   posp    = (const int*)d_in[5];
  const int*   depthp  = (const int*)d_in[6];
  const int*   maskp   = (const int*)d_in[7];
  const float* W_f     = (const float*)d_in[8];
  const float* b_f     = (const float*)d_in[9];
  const float* W_iou   = (const float*)d_in[10];
  const float* b_iou   = (const float*)d_in[11];
  float* out = (float*)d_out;
  int N = in_sizes[0] / H;
  int nhb = (N + 255) / 256;
  int maxb = NPOS + N / ROWSB;

  // ws layout
  unsigned short* wt = (unsigned short*)d_ws;          // 655360 * 2B
  int* hist2  = (int*)((char*)d_ws + (size_t)NPOS * 512 * H * 2);
  int* off2   = hist2 + nhb * 16;
  int* blkpos = off2 + nhb * 16;
  int* blkgs  = blkpos + maxb;
  int* blkcnt = blkgs + maxb;
  unsigned* order = (unsigned*)(blkcnt + maxb);

  int prep_blocks = NPOS * 16 + (NPOS * 384 * H) / 256 + nhb;
  hipLaunchKernelGGL(prep_wt, dim3(prep_blocks), dim3(256), 0, stream,
                     W_f, W_iou, wt, posp, hist2, N, nhb);
  hipLaunchKernelGGL(scan_build, dim3(1), dim3(640), 0, stream,
                     hist2, nhb, off2, blkpos, blkgs, blkcnt, maxb);
  hipLaunchKernelGGL(scatter_idx, dim3(nhb), dim3(256), 0, stream,
                     posp, depthp, maskp, off2, order, N);
  hipLaunchKernelGGL(tree_lstm_main, dim3(maxb), dim3(BLOCK), 0, stream,
                     child_h, child_c, e1, e2, h_prev,
                     b_f, b_iou, wt, order, blkpos, blkgs, blkcnt, out, N);
}